// Round 11
// baseline (203.074 us; speedup 1.0000x reference)
//
#include <hip/hip_runtime.h>
#include <math.h>

#define NVEC 65536                      // 64*32*32
#define OUT_LOSS 0
#define OUT_Q 1
#define OUT_PERP (1 + NVEC * 64)        // 4194305
#define OUT_IDX (1 + NVEC * 64 + 1)     // 4194306
#define EPS2 1e-4f                      // ambiguity margin (fast-path err bound ~2e-5)
#define FIX_CAP 16                      // per 32-vec group
#define NBLK 512
#define GRP 4                           // vec-groups (of 32) per block

typedef __attribute__((ext_vector_type(8))) short short8;   // 8 bf16 (4 VGPRs)
typedef __attribute__((ext_vector_type(4))) float float4v;  // MFMA acc

// ws layout (bytes): [0,512) double sse64[64] | [512,2560) u32 hist[512]

__device__ __forceinline__ unsigned short bf16_rn(float f) {
    unsigned u = __float_as_uint(f);
    return (unsigned short)((u + 0x7FFFu + ((u >> 16) & 1u)) >> 16);
}

// numpy pairwise_sum replica for sum(v*v) over 64 elems (products rounded
// before summing, 8 stride-8 chains, pairwise combine) — matches np.sum.
__device__ __forceinline__ float np_pairwise8_sq(const float* v) {
    float r[8];
#pragma unroll
    for (int j = 0; j < 8; ++j) r[j] = __fmul_rn(v[j], v[j]);
#pragma unroll
    for (int i = 8; i < 64; i += 8) {
#pragma unroll
        for (int j = 0; j < 8; ++j) r[j] = __fadd_rn(r[j], __fmul_rn(v[i + j], v[i + j]));
    }
    return __fadd_rn(__fadd_rn(__fadd_rn(r[0], r[1]), __fadd_rn(r[2], r[3])),
                     __fadd_rn(__fadd_rn(r[4], r[5]), __fadd_rn(r[6], r[7])));
}

// Persistent-block design: 1024 threads (16 waves) = whole CU. Stage the FULL
// converted codebook (hi/lo bf16 A-fragments, 128 KB) + csq into LDS once,
// then loop 4 vec-groups with all hot operands in LDS/regs (ds_read ~12 cyc
// vs ~200+ cyc L2 — rounds 8-10 were latency-bound on per-tile global frag
// loads, invariant to grid size). Grid 512 -> 2 sequential blocks/CU.
__launch_bounds__(1024, 4)   // 4 waves/EU = our 16-wave block; 128-VGPR budget (no round-9 spill)
__global__ void vq_main(const float* __restrict__ inputs, const float* __restrict__ codebook,
                        unsigned* __restrict__ hist, double* __restrict__ sse64,
                        float* __restrict__ out) {
    __shared__ short s_fhi[4096 * 8];    // 64 KB: A-frag hi [t=32][step=2][lane=64][8]
    __shared__ short s_flo[4096 * 8];    // 64 KB: A-frag lo
    __shared__ float s_csq[512];         // 2 KB (numpy-exact)
    __shared__ short s_bh[256 * 8];      // 4 KB: B-frag hi [vt=2][step=2][lane=64][8]
    __shared__ short s_bl[256 * 8];      // 4 KB
    __shared__ float s_A[32];
    __shared__ unsigned long long s_t1[16][32];   // 4 KB per-wave top1
    __shared__ unsigned long long s_t2[16][32];   // 4 KB per-wave top2
    __shared__ unsigned long long s_e[32];
    __shared__ int s_fix[FIX_CAP];
    __shared__ int s_nfix;
    __shared__ float s_w[16];
    // total ~150 KB <= 160 KB -> exactly 1 block/CU

    const int tid = threadIdx.x;
    const int wave = tid >> 6, lane = tid & 63;

    // ---- one-time: codebook -> A-fragments (hi/lo) + csq, all in LDS ----
    {
        const float4* cb4 = (const float4*)codebook;
#pragma unroll
        for (int c = 0; c < 4; ++c) {
            const int chunk = tid * 4 + c;           // 4096 8-float chunks
            const int row = chunk >> 3, col8 = chunk & 7;
            float4 f0 = cb4[chunk * 2 + 0], f1 = cb4[chunk * 2 + 1];
            const float fs[8] = {f0.x, f0.y, f0.z, f0.w, f1.x, f1.y, f1.z, f1.w};
            short8 h, l;
#pragma unroll
            for (int j = 0; j < 8; ++j) {
                unsigned short hv = bf16_rn(fs[j]);
                float lof = fs[j] - __uint_as_float(((unsigned)hv) << 16);
                h[j] = (short)hv;
                l[j] = (short)bf16_rn(lof);
            }
            const int t = row >> 4;
            const int ls = (row & 15) | ((col8 & 3) << 4);   // lane covering (m,kb)
            const int st = col8 >> 2;
            const int off = ((t * 2 + st) * 64 + ls) * 8;
            *(short8*)&s_fhi[off] = h;
            *(short8*)&s_flo[off] = l;
        }
        if (tid < 512) s_csq[tid] = np_pairwise8_sq(codebook + ((size_t)tid << 6));
    }

    float es = 0.f;   // per-thread SSE partial, accumulated across groups

#pragma unroll 1
    for (int g = 0; g < GRP; ++g) {
        const int vbase = (blockIdx.x * GRP + g) * 32;

        // per-group staging: B-frags (threads 0-255), exact A (256-287), nfix reset
        if (tid < 256) {
            const int vt = tid >> 7, st = (tid >> 6) & 1, ln = tid & 63;
            const int vrow = vt * 16 + (ln & 15);
            const int kb = st * 32 + (ln >> 4) * 8;
            const float4* xp = (const float4*)(inputs + ((size_t)(vbase + vrow) << 6) + kb);
            float4 f0 = xp[0], f1 = xp[1];
            const float fs[8] = {f0.x, f0.y, f0.z, f0.w, f1.x, f1.y, f1.z, f1.w};
            short8 h, l;
#pragma unroll
            for (int j = 0; j < 8; ++j) {
                unsigned short hv = bf16_rn(fs[j]);
                float lof = fs[j] - __uint_as_float(((unsigned)hv) << 16);
                h[j] = (short)hv;
                l[j] = (short)bf16_rn(lof);
            }
            const int off = ((vt * 2 + st) * 64 + ln) * 8;
            *(short8*)&s_bh[off] = h;
            *(short8*)&s_bl[off] = l;
        } else if (tid < 288) {
            s_A[tid - 256] = np_pairwise8_sq(inputs + ((size_t)(vbase + tid - 256) << 6));
        } else if (tid == 288) {
            s_nfix = 0;
        }
        __syncthreads();   // B0

        // B-frags to registers (8 ds_read_b128 = 32 VGPRs, persistent this group)
        short8 bh[2][2], bl[2][2];
#pragma unroll
        for (int vt = 0; vt < 2; ++vt)
#pragma unroll
            for (int st = 0; st < 2; ++st) {
                const int off = ((vt * 2 + st) * 64 + lane) * 8;
                bh[vt][st] = *(const short8*)&s_bh[off];
                bl[vt][st] = *(const short8*)&s_bl[off];
            }
        const float Av[2] = {s_A[lane & 15], s_A[16 + (lane & 15)]};

        unsigned long long e1[2] = {~0ULL, ~0ULL}, e2[2] = {~0ULL, ~0ULL};

#pragma unroll
        for (int tt = 0; tt < 2; ++tt) {            // this wave's 2 k-tiles
            const int t = wave * 2 + tt;
            const int fo = (t * 128 + lane) * 8;
            short8 ah0 = *(const short8*)&s_fhi[fo];
            short8 ah1 = *(const short8*)&s_fhi[fo + 512];
            short8 al0 = *(const short8*)&s_flo[fo];
            short8 al1 = *(const short8*)&s_flo[fo + 512];
            const int k0 = t * 16 + (lane >> 4) * 4;
            float4 cs = *(const float4*)&s_csq[k0];
            const float csr[4] = {cs.x, cs.y, cs.z, cs.w};
#pragma unroll
            for (int vt = 0; vt < 2; ++vt) {
                // split chains (2 + 4) to shorten the MFMA dependency path
                float4v a1 = {0.f, 0.f, 0.f, 0.f}, a2 = {0.f, 0.f, 0.f, 0.f};
                a1 = __builtin_amdgcn_mfma_f32_16x16x32_bf16(ah0, bh[vt][0], a1, 0, 0, 0);
                a1 = __builtin_amdgcn_mfma_f32_16x16x32_bf16(ah1, bh[vt][1], a1, 0, 0, 0);
                a2 = __builtin_amdgcn_mfma_f32_16x16x32_bf16(ah0, bl[vt][0], a2, 0, 0, 0);
                a2 = __builtin_amdgcn_mfma_f32_16x16x32_bf16(ah1, bl[vt][1], a2, 0, 0, 0);
                a2 = __builtin_amdgcn_mfma_f32_16x16x32_bf16(al0, bh[vt][0], a2, 0, 0, 0);
                a2 = __builtin_amdgcn_mfma_f32_16x16x32_bf16(al1, bh[vt][1], a2, 0, 0, 0);
#pragma unroll
                for (int r = 0; r < 4; ++r) {
                    // D: col=lane&15 (=vec in tile), row=(lane>>4)*4+r (=codeword)
                    float dot = __fadd_rn(a1[r], a2[r]);
                    float d2 = __fadd_rn(__fsub_rn(Av[vt], __fmul_rn(2.0f, dot)), csr[r]);
                    const unsigned k = (unsigned)(k0 + r);
                    unsigned long long e = ((unsigned long long)__float_as_uint(d2) << 32) | k;
                    if (e < e1[vt]) { e2[vt] = e1[vt]; e1[vt] = e; }
                    else if (e < e2[vt]) e2[vt] = e;
                }
            }
        }

        // merge 4 lane-groups (disjoint k-subsets, same vec), stash per wave
#pragma unroll
        for (int vt = 0; vt < 2; ++vt) {
#pragma unroll
            for (int off = 16; off <= 32; off <<= 1) {
                unsigned long long o1 = __shfl_xor(e1[vt], off);
                unsigned long long o2 = __shfl_xor(e2[vt], off);
                if (o1 < e1[vt]) { e2[vt] = (e1[vt] < o2) ? e1[vt] : o2; e1[vt] = o1; }
                else if (o1 < e2[vt]) e2[vt] = o1;
            }
            if (lane < 16) {
                s_t1[wave][vt * 16 + lane] = e1[vt];
                s_t2[wave][vt * 16 + lane] = e2[vt];
            }
        }
        __syncthreads();   // B1

        // 16-way tournament -> global top-2 per vec (u64 keeps first-occurrence)
        if (tid < 32) {
            unsigned long long E1 = ~0ULL, E2 = ~0ULL;
#pragma unroll
            for (int w = 0; w < 16; ++w) {
                unsigned long long a = s_t1[w][tid], b = s_t2[w][tid];
                if (a < E1) { E2 = (E1 < b) ? E1 : b; E1 = a; }
                else if (a < E2) E2 = a;
            }
            s_e[tid] = E1;
            float b1 = __uint_as_float((unsigned)(E1 >> 32));
            float b2 = __uint_as_float((unsigned)(E2 >> 32));
            if (__fsub_rn(b2, b1) <= EPS2) {   // ambiguous -> exact replay
                int pos = atomicAdd(&s_nfix, 1);
                if (pos < FIX_CAP) s_fix[pos] = tid;
            }
        }
        __syncthreads();   // B2

        // exact numpy-order replay for ambiguous vecs (one wave each; rare)
        {
            int nf = s_nfix; if (nf > FIX_CAP) nf = FIX_CAP;
            for (int f = wave; f < nf; f += 16) {
                const int vloc = s_fix[f];
                const float* xr = inputs + ((size_t)(vbase + vloc) << 6);  // wave-uniform
                const float A = s_A[vloc];
                unsigned long long best = ~0ULL;
#pragma unroll 1
                for (int r8 = 0; r8 < 8; ++r8) {
                    const int k = lane * 8 + r8;
                    const float* c = codebook + (k << 6);
                    float p[8] = {0.f, 0.f, 0.f, 0.f, 0.f, 0.f, 0.f, 0.f};
#pragma unroll
                    for (int ii = 0; ii < 64; ii += 8)
#pragma unroll
                        for (int j = 0; j < 8; ++j)
                            p[j] = __builtin_fmaf(xr[ii + j], c[ii + j], p[j]);
                    float dot = __fadd_rn(__fadd_rn(__fadd_rn(p[0], p[1]), __fadd_rn(p[2], p[3])),
                                          __fadd_rn(__fadd_rn(p[4], p[5]), __fadd_rn(p[6], p[7])));
                    float d2 = __fadd_rn(__fsub_rn(A, __fmul_rn(2.0f, dot)), s_csq[k]);
                    unsigned long long e =
                        ((unsigned long long)__float_as_uint(d2) << 32) | (unsigned)k;
                    if (e < best) best = e;
                }
#pragma unroll
                for (int off = 32; off > 0; off >>= 1) {
                    unsigned long long o = __shfl_down(best, off);
                    if (o < best) best = o;
                }
                if (lane == 0) s_e[vloc] = best;   // equal-d2 ties -> smallest k
            }
        }
        __syncthreads();   // B3

        // epilogue: indices + hist + quantized (fully coalesced float2) + sse
        if (tid < 32) {
            const unsigned kf = (unsigned)s_e[tid];
            out[OUT_IDX + vbase + tid] = (float)kf;
            atomicAdd(&hist[kf], 1u);
        }
        {
            const int row = tid >> 5, c2 = (tid & 31) * 2;
            const unsigned k = (unsigned)s_e[row];
            const float2 qv = *(const float2*)(codebook + ((size_t)k << 6) + c2);
            *(float2*)(out + OUT_Q + ((size_t)(vbase + row) << 6) + c2) = qv;
            const float2 xv = *(const float2*)(inputs + ((size_t)(vbase + row) << 6) + c2);
            float d0 = qv.x - xv.x; es = __builtin_fmaf(d0, d0, es);
            float d1 = qv.y - xv.y; es = __builtin_fmaf(d1, d1, es);
        }
        // no barrier here: next group's LDS writers (s_bh/s_A/s_nfix) only run
        // post-B3; s_e next written post-B1(g+1) — two barriers downstream.
    }

    // block SSE reduction -> one double atomic
#pragma unroll
    for (int off = 32; off > 0; off >>= 1) es += __shfl_down(es, off);
    if (lane == 0) s_w[wave] = es;
    __syncthreads();
    if (tid == 0) {
        float S = 0.f;
#pragma unroll
        for (int i = 0; i < 16; ++i) S += s_w[i];
        atomicAdd(&sse64[blockIdx.x & 63], (double)S);
    }
}

// final stats: kernel boundary gives device-wide visibility of hist/sse
__global__ void vq_final(const unsigned* __restrict__ hist, const double* __restrict__ sse64,
                         float* __restrict__ out) {
    __shared__ float s_wsm[8];
    const int k = threadIdx.x;  // 512 threads
    float pr = (float)hist[k] / 65536.0f;
    float v = __fmul_rn(pr, logf(__fadd_rn(pr, 1e-10f)));
#pragma unroll
    for (int off = 32; off > 0; off >>= 1) v += __shfl_down(v, off);
    if ((k & 63) == 0) s_wsm[k >> 6] = v;
    __syncthreads();
    if (k == 0) {
        float S = 0.f;
#pragma unroll
        for (int i = 0; i < 8; ++i) S += s_wsm[i];
        out[OUT_PERP] = expf(-S);
        double sv = 0.0;
        for (int i = 0; i < 64; ++i) sv += sse64[i];
        float m = (float)(sv / 4194304.0);            // exact /2^22
        out[OUT_LOSS] = __fadd_rn(m, __fmul_rn(0.25f, m));
    }
}

extern "C" void kernel_launch(void* const* d_in, const int* in_sizes, int n_in,
                              void* d_out, int out_size, void* d_ws, size_t ws_size,
                              hipStream_t stream) {
    const float* inputs   = (const float*)d_in[0];
    const float* codebook = (const float*)d_in[1];
    float* out = (float*)d_out;
    double*   sse64 = (double*)d_ws;
    unsigned* hist  = (unsigned*)((char*)d_ws + 512);

    hipMemsetAsync(d_ws, 0, 2560, stream);
    vq_main<<<NBLK, 1024, 0, stream>>>(inputs, codebook, hist, sse64, out);
    vq_final<<<1, 512, 0, stream>>>(hist, sse64, out);
}